// Round 8
// baseline (692.248 us; speedup 1.0000x reference)
//
#include <hip/hip_runtime.h>
#include <math.h>

#define BATCH 32768
#define NCLS  1000
#define NV4   250            // NCLS / 4
#define ALPHA 0.1f
#define GRID  2048
#define NWAVE (GRID * 4)     // 8192 waves; 3*BATCH / NWAVE = 12 rows/wave = 6 pairs
#define NPAIR 6
#define NPASS 4              // diagnostic amplification: kernel does the job 4x, result /4

struct Scalars {
    float th1, th2, bb, bias, gamma, inv_norm, invB;
};

// Row I (0..11) for wave `gwave` (< NWAVE): I<4 -> outputs rows, I>=4 -> classifier rows.
template <int I>
__device__ __forceinline__ void row_meta(int gwave,
                                         const float* __restrict__ outputs,
                                         const float* __restrict__ oc,
                                         const int* __restrict__ labels,
                                         const float*& base, int& label) {
    if constexpr (I < 4) {
        const int r = gwave + I * NWAVE;          // < BATCH
        base = outputs + (size_t)r * NCLS;
        label = labels[r];
    } else {
        const int r2 = gwave + (I - 4) * NWAVE;   // row into oc, in [0, 2*BATCH)
        base = oc + (size_t)r2 * NCLS;
        label = labels[(I < 8) ? r2 : (gwave + (I - 8) * NWAVE)];
    }
}

__device__ __forceinline__ void load_row(float (&v)[16], float& x,
                                         const float* __restrict__ base, int label, int lane) {
    const float4* p = (const float4*)base;
    #pragma unroll
    for (int j = 0; j < 4; ++j) {
        const int idx = lane + j * 64;
        float4 q;
        if (idx < NV4) q = p[idx];
        else           q = make_float4(-INFINITY, -INFINITY, -INFINITY, -INFINITY);
        v[4 * j + 0] = q.x; v[4 * j + 1] = q.y;
        v[4 * j + 2] = q.z; v[4 * j + 3] = q.w;
    }
    x = base[label];   // uniform; same lines as the vector loads -> cache hit
}

// Two rows reduced with fully interleaved (independent) chains.
template <bool IS_OUT>
__device__ __forceinline__ float process_pair(const float (&a)[16], float xa,
                                              const float (&b)[16], float xb,
                                              const Scalars& sc) {
    float contrib;
    if constexpr (IS_OUT) {
        float a0 = -INFINITY, a1 = -INFINITY, b0 = -INFINITY, b1 = -INFINITY;
        #pragma unroll
        for (int j = 0; j < 16; ++j) {
            const float av = a[j], bv = b[j];
            const float na1 = fmaxf(a1, fminf(a0, av));
            const float nb1 = fmaxf(b1, fminf(b0, bv));
            a0 = fmaxf(a0, av); a1 = na1;
            b0 = fmaxf(b0, bv); b1 = nb1;
        }
        #pragma unroll
        for (int off = 32; off; off >>= 1) {
            const float oa0 = __shfl_xor(a0, off, 64);
            const float oa1 = __shfl_xor(a1, off, 64);
            const float ob0 = __shfl_xor(b0, off, 64);
            const float ob1 = __shfl_xor(b1, off, 64);
            const float na1 = fmaxf(fminf(a0, oa0), fmaxf(a1, oa1));
            const float nb1 = fmaxf(fminf(b0, ob0), fmaxf(b1, ob1));
            a0 = fmaxf(a0, oa0); a1 = na1;
            b0 = fmaxf(b0, ob0); b1 = nb1;
        }
        float sa = 0.0f, sb = 0.0f;
        #pragma unroll
        for (int j = 0; j < 16; ++j) {
            sa += __expf(a[j] - a0);
            sb += __expf(b[j] - b0);
        }
        #pragma unroll
        for (int off = 32; off; off >>= 1) {
            sa += __shfl_xor(sa, off, 64);
            sb += __shfl_xor(sb, off, 64);
        }
        const float lseA = a0 + __logf(sa);
        const float lseB = b0 + __logf(sb);
        contrib = (lseA - xa + lseB - xb) * sc.invB;
        const float ya = (a0 == xa) ? a1 : ((a1 == xa) ? a0 : (a0 + a1));
        const float yb = (b0 == xb) ? b1 : ((b1 == xb) ? b0 : (b0 + b1));
        const float da = (sc.th1 * xa + sc.th2 * ya + sc.bb - sc.bias) * sc.inv_norm;
        const float db = (sc.th1 * xb + sc.th2 * yb + sc.bb - sc.bias) * sc.inv_norm;
        const float pa = (da >= 10.0f) ? -2.0f : ((da >= 0.0f) ? (-sc.gamma * da) : (-da));
        const float pb = (db >= 10.0f) ? -2.0f : ((db >= 0.0f) ? (-sc.gamma * db) : (-db));
        contrib += ALPHA * (pa + pb);
    } else {
        float ma = a[0], mb = b[0];
        #pragma unroll
        for (int j = 1; j < 16; ++j) {
            ma = fmaxf(ma, a[j]);
            mb = fmaxf(mb, b[j]);
        }
        #pragma unroll
        for (int off = 32; off; off >>= 1) {
            ma = fmaxf(ma, __shfl_xor(ma, off, 64));
            mb = fmaxf(mb, __shfl_xor(mb, off, 64));
        }
        float sa = 0.0f, sb = 0.0f;
        #pragma unroll
        for (int j = 0; j < 16; ++j) {
            sa += __expf(a[j] - ma);
            sb += __expf(b[j] - mb);
        }
        #pragma unroll
        for (int off = 32; off; off >>= 1) {
            sa += __shfl_xor(sa, off, 64);
            sb += __shfl_xor(sb, off, 64);
        }
        const float lseA = ma + __logf(sa);
        const float lseB = mb + __logf(sb);
        contrib = (lseA - xa + lseB - xb) * sc.invB;
    }
    return contrib;
}

// Pair-pipelined walk: prefetch pair P+1 while reducing pair P.
template <int P>
__device__ __forceinline__ void pstep(float (&ca)[16], float& xca, float (&cb)[16], float& xcb,
                                      float (&na)[16], float& xna, float (&nb)[16], float& xnb,
                                      float& acc, int gwave, int lane,
                                      const float* __restrict__ outputs,
                                      const float* __restrict__ oc,
                                      const int* __restrict__ labels,
                                      const Scalars& sc) {
    if constexpr (P + 1 < NPAIR) {
        const float* b0; int l0;
        row_meta<2 * (P + 1)>(gwave, outputs, oc, labels, b0, l0);
        load_row(na, xna, b0, l0, lane);
        const float* b1; int l1;
        row_meta<2 * (P + 1) + 1>(gwave, outputs, oc, labels, b1, l1);
        load_row(nb, xnb, b1, l1, lane);
    }
    acc += process_pair<(P < 2)>(ca, xca, cb, xcb, sc);
    if constexpr (P + 1 < NPAIR) {
        pstep<P + 1>(na, xna, nb, xnb, ca, xca, cb, xcb,
                     acc, gwave, lane, outputs, oc, labels, sc);
    }
}

__global__ __launch_bounds__(256, 4) void loss_kernel(
    const float* __restrict__ outputs,      // [B, C]
    const float* __restrict__ oc,           // [2, B, C]
    const int*   __restrict__ labels,       // [B]
    const float* __restrict__ wb,           // [3]
    const float* __restrict__ ab,           // [1]
    const float* __restrict__ ag,           // [1]
    float* __restrict__ out)                // [1]
{
    const int lane  = threadIdx.x & 63;
    const int wave  = threadIdx.x >> 6;
    const int gwave = blockIdx.x * 4 + wave;

    Scalars sc;
    sc.th1 = wb[0]; sc.th2 = wb[1]; sc.bb = wb[2];
    sc.bias = ab[0]; sc.gamma = ag[0];
    sc.inv_norm = 1.0f / sqrtf(sc.th1 * sc.th1 + sc.th2 * sc.th2);
    sc.invB = 1.0f / (float)BATCH;

    float acc = 0.0f;

    // DIAGNOSTIC: run the full reduction NPASS times so the kernel dispatch
    // is long enough to surface in the rocprof top-5 with its own counters.
    // Result is divided by NPASS (error <= 1 ulp).
    #pragma unroll 1
    for (int pass = 0; pass < NPASS; ++pass) {
        float va[16], vb[16], wa[16], wbuf[16];
        float xva = 0.0f, xvb = 0.0f, xwa = 0.0f, xwb = 0.0f;
        {
            const float* b0; int l0;
            row_meta<0>(gwave, outputs, oc, labels, b0, l0);
            load_row(va, xva, b0, l0, lane);
            const float* b1; int l1;
            row_meta<1>(gwave, outputs, oc, labels, b1, l1);
            load_row(vb, xvb, b1, l1, lane);
        }
        pstep<0>(va, xva, vb, xvb, wa, xwa, wbuf, xwb,
                 acc, gwave, lane, outputs, oc, labels, sc);
    }
    acc *= (1.0f / (float)NPASS);

    // block reduce: one partial per wave, one atomic per block
    __shared__ float wacc[4];
    if (lane == 0) wacc[wave] = acc;
    __syncthreads();
    if (threadIdx.x == 0) {
        float t = wacc[0] + wacc[1] + wacc[2] + wacc[3];
        atomicAdd(out, t);
    }
}

extern "C" void kernel_launch(void* const* d_in, const int* in_sizes, int n_in,
                              void* d_out, int out_size, void* d_ws, size_t ws_size,
                              hipStream_t stream) {
    const float* outputs = (const float*)d_in[0];
    const float* oc      = (const float*)d_in[1];
    const int*   labels  = (const int*)d_in[2];
    const float* wb      = (const float*)d_in[3];
    const float* ab      = (const float*)d_in[4];
    const float* ag      = (const float*)d_in[5];
    float* out = (float*)d_out;

    hipMemsetAsync(out, 0, (size_t)out_size * sizeof(float), stream);  // d_out is poisoned before every launch
    loss_kernel<<<dim3(GRID), dim3(256), 0, stream>>>(outputs, oc, labels, wb, ab, ag, out);
}

// Round 9
// 485.842 us; speedup vs baseline: 1.4248x; 1.4248x over previous
//
#include <hip/hip_runtime.h>
#include <math.h>

#define BATCH 32768
#define NCLS  1000
#define NV4   250            // NCLS / 4
#define ALPHA 0.1f
#define GRID  4096
#define NWAVE (GRID * 4)     // 16384 waves; 3*BATCH / NWAVE = 6 rows/wave = 3 pairs
#define NPAIR 3
#define NPASS 4              // diagnostic amplification: kernel does the job 4x, result /4

struct Scalars {
    float th1, th2, bb, bias, gamma, inv_norm, invB;
};

// ---------- DPP wave64 reductions (VALU pipe, no DS ops) ----------
// ctrl: 0x111..0x118 = row_shr:1/2/4/8, 0x142 = row_bcast15, 0x143 = row_bcast31
template <int CTRL>
__device__ __forceinline__ float dpp_get_self(float x) {
    // invalid source lanes receive old (= x) -> op(x,x) is a no-op for max
    return __int_as_float(__builtin_amdgcn_update_dpp(
        __float_as_int(x), __float_as_int(x), CTRL, 0xf, 0xf, false));
}
template <int CTRL>
__device__ __forceinline__ float dpp_get_zero(float x) {
    // invalid source lanes read 0 -> adding 0 is a no-op for sum
    return __int_as_float(__builtin_amdgcn_update_dpp(
        0, __float_as_int(x), CTRL, 0xf, 0xf, true));
}
__device__ __forceinline__ float dpp_max_reduce(float x) {
    x = fmaxf(x, dpp_get_self<0x111>(x));
    x = fmaxf(x, dpp_get_self<0x112>(x));
    x = fmaxf(x, dpp_get_self<0x114>(x));
    x = fmaxf(x, dpp_get_self<0x118>(x));   // lane15 of each row-of-16 = row max
    x = fmaxf(x, dpp_get_self<0x142>(x));   // lane31 = max rows0-1, lane63 = max rows2-3
    x = fmaxf(x, dpp_get_self<0x143>(x));   // lane63 = global max
    return __int_as_float(__builtin_amdgcn_readlane(__float_as_int(x), 63));
}
__device__ __forceinline__ float dpp_sum_reduce(float x) {
    x += dpp_get_zero<0x111>(x);
    x += dpp_get_zero<0x112>(x);
    x += dpp_get_zero<0x114>(x);
    x += dpp_get_zero<0x118>(x);
    x += dpp_get_zero<0x142>(x);
    x += dpp_get_zero<0x143>(x);
    return __int_as_float(__builtin_amdgcn_readlane(__float_as_int(x), 63));
}

// Row I (0..5) for wave `gwave` (< NWAVE): I<2 -> outputs rows, I>=2 -> classifier rows.
template <int I>
__device__ __forceinline__ void row_meta(int gwave,
                                         const float* __restrict__ outputs,
                                         const float* __restrict__ oc,
                                         const int* __restrict__ labels,
                                         const float*& base, int& label) {
    if constexpr (I < 2) {
        const int r = gwave + I * NWAVE;          // < BATCH
        base = outputs + (size_t)r * NCLS;
        label = labels[r];
    } else {
        const int r2 = gwave + (I - 2) * NWAVE;   // row into oc, in [0, 2*BATCH)
        base = oc + (size_t)r2 * NCLS;
        label = labels[(I < 4) ? r2 : (gwave + (I - 4) * NWAVE)];
    }
}

__device__ __forceinline__ void load_row(float (&v)[16], float& x,
                                         const float* __restrict__ base, int label, int lane) {
    const float4* p = (const float4*)base;
    #pragma unroll
    for (int j = 0; j < 4; ++j) {
        const int idx = lane + j * 64;
        float4 q;
        if (idx < NV4) q = p[idx];
        else           q = make_float4(-INFINITY, -INFINITY, -INFINITY, -INFINITY);
        v[4 * j + 0] = q.x; v[4 * j + 1] = q.y;
        v[4 * j + 2] = q.z; v[4 * j + 3] = q.w;
    }
    x = base[label];   // uniform; same lines as the vector loads -> cache hit
}

// Two rows reduced with interleaved (independent) chains.
template <bool IS_OUT>
__device__ __forceinline__ float process_pair(const float (&a)[16], float xa,
                                              const float (&b)[16], float xb,
                                              const Scalars& sc) {
    float contrib;
    if constexpr (IS_OUT) {
        // top-2 butterfly kept on shfl (self-merge is not idempotent for top-2)
        float a0 = -INFINITY, a1 = -INFINITY, b0 = -INFINITY, b1 = -INFINITY;
        #pragma unroll
        for (int j = 0; j < 16; ++j) {
            const float av = a[j], bv = b[j];
            const float na1 = fmaxf(a1, fminf(a0, av));
            const float nb1 = fmaxf(b1, fminf(b0, bv));
            a0 = fmaxf(a0, av); a1 = na1;
            b0 = fmaxf(b0, bv); b1 = nb1;
        }
        #pragma unroll
        for (int off = 32; off; off >>= 1) {
            const float oa0 = __shfl_xor(a0, off, 64);
            const float oa1 = __shfl_xor(a1, off, 64);
            const float ob0 = __shfl_xor(b0, off, 64);
            const float ob1 = __shfl_xor(b1, off, 64);
            const float na1 = fmaxf(fminf(a0, oa0), fmaxf(a1, oa1));
            const float nb1 = fmaxf(fminf(b0, ob0), fmaxf(b1, ob1));
            a0 = fmaxf(a0, oa0); a1 = na1;
            b0 = fmaxf(b0, ob0); b1 = nb1;
        }
        float sa = 0.0f, sb = 0.0f;
        #pragma unroll
        for (int j = 0; j < 16; ++j) {
            sa += __expf(a[j] - a0);
            sb += __expf(b[j] - b0);
        }
        sa = dpp_sum_reduce(sa);
        sb = dpp_sum_reduce(sb);
        const float lseA = a0 + __logf(sa);
        const float lseB = b0 + __logf(sb);
        contrib = (lseA - xa + lseB - xb) * sc.invB;
        const float ya = (a0 == xa) ? a1 : ((a1 == xa) ? a0 : (a0 + a1));
        const float yb = (b0 == xb) ? b1 : ((b1 == xb) ? b0 : (b0 + b1));
        const float da = (sc.th1 * xa + sc.th2 * ya + sc.bb - sc.bias) * sc.inv_norm;
        const float db = (sc.th1 * xb + sc.th2 * yb + sc.bb - sc.bias) * sc.inv_norm;
        const float pa = (da >= 10.0f) ? -2.0f : ((da >= 0.0f) ? (-sc.gamma * da) : (-da));
        const float pb = (db >= 10.0f) ? -2.0f : ((db >= 0.0f) ? (-sc.gamma * db) : (-db));
        contrib += ALPHA * (pa + pb);
    } else {
        float ma = a[0], mb = b[0];
        #pragma unroll
        for (int j = 1; j < 16; ++j) {
            ma = fmaxf(ma, a[j]);
            mb = fmaxf(mb, b[j]);
        }
        ma = dpp_max_reduce(ma);
        mb = dpp_max_reduce(mb);
        float sa = 0.0f, sb = 0.0f;
        #pragma unroll
        for (int j = 0; j < 16; ++j) {
            sa += __expf(a[j] - ma);
            sb += __expf(b[j] - mb);
        }
        sa = dpp_sum_reduce(sa);
        sb = dpp_sum_reduce(sb);
        const float lseA = ma + __logf(sa);
        const float lseB = mb + __logf(sb);
        contrib = (lseA - xa + lseB - xb) * sc.invB;
    }
    return contrib;
}

// Pair-pipelined walk: prefetch pair P+1 while reducing pair P.
template <int P>
__device__ __forceinline__ void pstep(float (&ca)[16], float& xca, float (&cb)[16], float& xcb,
                                      float (&na)[16], float& xna, float (&nb)[16], float& xnb,
                                      float& acc, int gwave, int lane,
                                      const float* __restrict__ outputs,
                                      const float* __restrict__ oc,
                                      const int* __restrict__ labels,
                                      const Scalars& sc) {
    if constexpr (P + 1 < NPAIR) {
        const float* b0; int l0;
        row_meta<2 * (P + 1)>(gwave, outputs, oc, labels, b0, l0);
        load_row(na, xna, b0, l0, lane);
        const float* b1; int l1;
        row_meta<2 * (P + 1) + 1>(gwave, outputs, oc, labels, b1, l1);
        load_row(nb, xnb, b1, l1, lane);
    }
    acc += process_pair<(P < 1)>(ca, xca, cb, xcb, sc);
    if constexpr (P + 1 < NPAIR) {
        pstep<P + 1>(na, xna, nb, xnb, ca, xca, cb, xcb,
                     acc, gwave, lane, outputs, oc, labels, sc);
    }
}

__global__ __launch_bounds__(256, 4) void loss_kernel(
    const float* __restrict__ outputs,      // [B, C]
    const float* __restrict__ oc,           // [2, B, C]
    const int*   __restrict__ labels,       // [B]
    const float* __restrict__ wb,           // [3]
    const float* __restrict__ ab,           // [1]
    const float* __restrict__ ag,           // [1]
    float* __restrict__ out)                // [1]
{
    const int lane  = threadIdx.x & 63;
    const int wave  = threadIdx.x >> 6;
    const int gwave = blockIdx.x * 4 + wave;

    Scalars sc;
    sc.th1 = wb[0]; sc.th2 = wb[1]; sc.bb = wb[2];
    sc.bias = ab[0]; sc.gamma = ag[0];
    sc.inv_norm = 1.0f / sqrtf(sc.th1 * sc.th1 + sc.th2 * sc.th2);
    sc.invB = 1.0f / (float)BATCH;

    float acc = 0.0f;

    // DIAGNOSTIC: run the full reduction NPASS times so the kernel dispatch
    // surfaces in the rocprof top-5 with its own counters. Result / NPASS.
    #pragma unroll 1
    for (int pass = 0; pass < NPASS; ++pass) {
        float va[16], vb[16], wa[16], wbuf[16];
        float xva = 0.0f, xvb = 0.0f, xwa = 0.0f, xwb = 0.0f;
        {
            const float* b0; int l0;
            row_meta<0>(gwave, outputs, oc, labels, b0, l0);
            load_row(va, xva, b0, l0, lane);
            const float* b1; int l1;
            row_meta<1>(gwave, outputs, oc, labels, b1, l1);
            load_row(vb, xvb, b1, l1, lane);
        }
        pstep<0>(va, xva, vb, xvb, wa, xwa, wbuf, xwb,
                 acc, gwave, lane, outputs, oc, labels, sc);
    }
    acc *= (1.0f / (float)NPASS);

    // block reduce: one partial per wave, one atomic per block
    __shared__ float wacc[4];
    if (lane == 0) wacc[wave] = acc;
    __syncthreads();
    if (threadIdx.x == 0) {
        float t = wacc[0] + wacc[1] + wacc[2] + wacc[3];
        atomicAdd(out, t);
    }
}

extern "C" void kernel_launch(void* const* d_in, const int* in_sizes, int n_in,
                              void* d_out, int out_size, void* d_ws, size_t ws_size,
                              hipStream_t stream) {
    const float* outputs = (const float*)d_in[0];
    const float* oc      = (const float*)d_in[1];
    const int*   labels  = (const int*)d_in[2];
    const float* wb      = (const float*)d_in[3];
    const float* ab      = (const float*)d_in[4];
    const float* ag      = (const float*)d_in[5];
    float* out = (float*)d_out;

    hipMemsetAsync(out, 0, (size_t)out_size * sizeof(float), stream);  // d_out is poisoned before every launch
    loss_kernel<<<dim3(GRID), dim3(256), 0, stream>>>(outputs, oc, labels, wb, ab, ag, out);
}

// Round 11
// 427.762 us; speedup vs baseline: 1.6183x; 1.1358x over previous
//
#include <hip/hip_runtime.h>
#include <math.h>

#define BATCH 32768
#define NCLS  1000
#define NV4   250            // NCLS / 4
#define ALPHA 0.1f
#define GRID  4096
#define NWAVE (GRID * 4)     // 16384 waves; 3*BATCH / NWAVE = 6 rows/wave = 3 pairs
#define NPAIR 3

struct Scalars {
    float th1, th2, bb, bias, gamma, inv_norm, invB;
};

// ---------- DPP wave64 reductions (VALU pipe, no DS ops) ----------
// ctrl: 0x111..0x118 = row_shr:1/2/4/8, 0x142 = row_bcast15, 0x143 = row_bcast31
template <int CTRL>
__device__ __forceinline__ float dpp_get_self(float x) {
    // invalid source lanes receive old (= x) -> op(x,x) is a no-op for max
    return __int_as_float(__builtin_amdgcn_update_dpp(
        __float_as_int(x), __float_as_int(x), CTRL, 0xf, 0xf, false));
}
template <int CTRL>
__device__ __forceinline__ float dpp_get_zero(float x) {
    // invalid source lanes read 0 -> adding 0 is a no-op for sum
    return __int_as_float(__builtin_amdgcn_update_dpp(
        0, __float_as_int(x), CTRL, 0xf, 0xf, true));
}
__device__ __forceinline__ float dpp_max_reduce(float x) {
    x = fmaxf(x, dpp_get_self<0x111>(x));
    x = fmaxf(x, dpp_get_self<0x112>(x));
    x = fmaxf(x, dpp_get_self<0x114>(x));
    x = fmaxf(x, dpp_get_self<0x118>(x));   // lane15 of each row-of-16 = row max
    x = fmaxf(x, dpp_get_self<0x142>(x));   // lane31 = max rows0-1, lane63 = max rows2-3
    x = fmaxf(x, dpp_get_self<0x143>(x));   // lane63 = global max
    return __int_as_float(__builtin_amdgcn_readlane(__float_as_int(x), 63));
}
__device__ __forceinline__ float dpp_sum_reduce(float x) {
    x += dpp_get_zero<0x111>(x);
    x += dpp_get_zero<0x112>(x);
    x += dpp_get_zero<0x114>(x);
    x += dpp_get_zero<0x118>(x);
    x += dpp_get_zero<0x142>(x);
    x += dpp_get_zero<0x143>(x);
    return __int_as_float(__builtin_amdgcn_readlane(__float_as_int(x), 63));
}

// Row I (0..5) for wave `gwave` (< NWAVE): I<2 -> outputs rows, I>=2 -> classifier rows.
template <int I>
__device__ __forceinline__ void row_meta(int gwave,
                                         const float* __restrict__ outputs,
                                         const float* __restrict__ oc,
                                         const int* __restrict__ labels,
                                         const float*& base, int& label) {
    if constexpr (I < 2) {
        const int r = gwave + I * NWAVE;          // < BATCH
        base = outputs + (size_t)r * NCLS;
        label = labels[r];
    } else {
        const int r2 = gwave + (I - 2) * NWAVE;   // row into oc, in [0, 2*BATCH)
        base = oc + (size_t)r2 * NCLS;
        label = labels[(I < 4) ? r2 : (gwave + (I - 4) * NWAVE)];
    }
}

__device__ __forceinline__ void load_row(float (&v)[16], float& x,
                                         const float* __restrict__ base, int label, int lane) {
    const float4* p = (const float4*)base;
    #pragma unroll
    for (int j = 0; j < 4; ++j) {
        const int idx = lane + j * 64;
        float4 q;
        if (idx < NV4) q = p[idx];
        else           q = make_float4(-INFINITY, -INFINITY, -INFINITY, -INFINITY);
        v[4 * j + 0] = q.x; v[4 * j + 1] = q.y;
        v[4 * j + 2] = q.z; v[4 * j + 3] = q.w;
    }
    x = base[label];   // uniform; same lines as the vector loads -> cache hit
}

// Two rows reduced with interleaved (independent) chains.
template <bool IS_OUT>
__device__ __forceinline__ float process_pair(const float (&a)[16], float xa,
                                              const float (&b)[16], float xb,
                                              const Scalars& sc) {
    float contrib;
    if constexpr (IS_OUT) {
        // top-2 butterfly kept on shfl (self-merge is not idempotent for top-2)
        float a0 = -INFINITY, a1 = -INFINITY, b0 = -INFINITY, b1 = -INFINITY;
        #pragma unroll
        for (int j = 0; j < 16; ++j) {
            const float av = a[j], bv = b[j];
            const float na1 = fmaxf(a1, fminf(a0, av));
            const float nb1 = fmaxf(b1, fminf(b0, bv));
            a0 = fmaxf(a0, av); a1 = na1;
            b0 = fmaxf(b0, bv); b1 = nb1;
        }
        #pragma unroll
        for (int off = 32; off; off >>= 1) {
            const float oa0 = __shfl_xor(a0, off, 64);
            const float oa1 = __shfl_xor(a1, off, 64);
            const float ob0 = __shfl_xor(b0, off, 64);
            const float ob1 = __shfl_xor(b1, off, 64);
            const float na1 = fmaxf(fminf(a0, oa0), fmaxf(a1, oa1));
            const float nb1 = fmaxf(fminf(b0, ob0), fmaxf(b1, ob1));
            a0 = fmaxf(a0, oa0); a1 = na1;
            b0 = fmaxf(b0, ob0); b1 = nb1;
        }
        float sa = 0.0f, sb = 0.0f;
        #pragma unroll
        for (int j = 0; j < 16; ++j) {
            sa += __expf(a[j] - a0);
            sb += __expf(b[j] - b0);
        }
        sa = dpp_sum_reduce(sa);
        sb = dpp_sum_reduce(sb);
        const float lseA = a0 + __logf(sa);
        const float lseB = b0 + __logf(sb);
        contrib = (lseA - xa + lseB - xb) * sc.invB;
        const float ya = (a0 == xa) ? a1 : ((a1 == xa) ? a0 : (a0 + a1));
        const float yb = (b0 == xb) ? b1 : ((b1 == xb) ? b0 : (b0 + b1));
        const float da = (sc.th1 * xa + sc.th2 * ya + sc.bb - sc.bias) * sc.inv_norm;
        const float db = (sc.th1 * xb + sc.th2 * yb + sc.bb - sc.bias) * sc.inv_norm;
        const float pa = (da >= 10.0f) ? -2.0f : ((da >= 0.0f) ? (-sc.gamma * da) : (-da));
        const float pb = (db >= 10.0f) ? -2.0f : ((db >= 0.0f) ? (-sc.gamma * db) : (-db));
        contrib += ALPHA * (pa + pb);
    } else {
        float ma = a[0], mb = b[0];
        #pragma unroll
        for (int j = 1; j < 16; ++j) {
            ma = fmaxf(ma, a[j]);
            mb = fmaxf(mb, b[j]);
        }
        ma = dpp_max_reduce(ma);
        mb = dpp_max_reduce(mb);
        float sa = 0.0f, sb = 0.0f;
        #pragma unroll
        for (int j = 0; j < 16; ++j) {
            sa += __expf(a[j] - ma);
            sb += __expf(b[j] - mb);
        }
        sa = dpp_sum_reduce(sa);
        sb = dpp_sum_reduce(sb);
        const float lseA = ma + __logf(sa);
        const float lseB = mb + __logf(sb);
        contrib = (lseA - xa + lseB - xb) * sc.invB;
    }
    return contrib;
}

// Pair-pipelined walk: prefetch pair P+1 while reducing pair P.
template <int P>
__device__ __forceinline__ void pstep(float (&ca)[16], float& xca, float (&cb)[16], float& xcb,
                                      float (&na)[16], float& xna, float (&nb)[16], float& xnb,
                                      float& acc, int gwave, int lane,
                                      const float* __restrict__ outputs,
                                      const float* __restrict__ oc,
                                      const int* __restrict__ labels,
                                      const Scalars& sc) {
    if constexpr (P + 1 < NPAIR) {
        const float* b0; int l0;
        row_meta<2 * (P + 1)>(gwave, outputs, oc, labels, b0, l0);
        load_row(na, xna, b0, l0, lane);
        const float* b1; int l1;
        row_meta<2 * (P + 1) + 1>(gwave, outputs, oc, labels, b1, l1);
        load_row(nb, xnb, b1, l1, lane);
    }
    acc += process_pair<(P < 1)>(ca, xca, cb, xcb, sc);
    if constexpr (P + 1 < NPAIR) {
        pstep<P + 1>(na, xna, nb, xnb, ca, xca, cb, xcb,
                     acc, gwave, lane, outputs, oc, labels, sc);
    }
}

__global__ __launch_bounds__(256, 4) void loss_kernel(
    const float* __restrict__ outputs,      // [B, C]
    const float* __restrict__ oc,           // [2, B, C]
    const int*   __restrict__ labels,       // [B]
    const float* __restrict__ wb,           // [3]
    const float* __restrict__ ab,           // [1]
    const float* __restrict__ ag,           // [1]
    float* __restrict__ out)                // [1]
{
    const int lane  = threadIdx.x & 63;
    const int wave  = threadIdx.x >> 6;
    const int gwave = blockIdx.x * 4 + wave;

    Scalars sc;
    sc.th1 = wb[0]; sc.th2 = wb[1]; sc.bb = wb[2];
    sc.bias = ab[0]; sc.gamma = ag[0];
    sc.inv_norm = 1.0f / sqrtf(sc.th1 * sc.th1 + sc.th2 * sc.th2);
    sc.invB = 1.0f / (float)BATCH;

    float acc = 0.0f;
    float va[16], vb[16], wa[16], wbuf[16];
    float xva = 0.0f, xvb = 0.0f, xwa = 0.0f, xwb = 0.0f;

    {
        const float* b0; int l0;
        row_meta<0>(gwave, outputs, oc, labels, b0, l0);
        load_row(va, xva, b0, l0, lane);
        const float* b1; int l1;
        row_meta<1>(gwave, outputs, oc, labels, b1, l1);
        load_row(vb, xvb, b1, l1, lane);
    }
    pstep<0>(va, xva, vb, xvb, wa, xwa, wbuf, xwb,
             acc, gwave, lane, outputs, oc, labels, sc);

    // block reduce: one partial per wave, one atomic per block
    __shared__ float wacc[4];
    if (lane == 0) wacc[wave] = acc;
    __syncthreads();
    if (threadIdx.x == 0) {
        float t = wacc[0] + wacc[1] + wacc[2] + wacc[3];
        atomicAdd(out, t);
    }
}

extern "C" void kernel_launch(void* const* d_in, const int* in_sizes, int n_in,
                              void* d_out, int out_size, void* d_ws, size_t ws_size,
                              hipStream_t stream) {
    const float* outputs = (const float*)d_in[0];
    const float* oc      = (const float*)d_in[1];
    const int*   labels  = (const int*)d_in[2];
    const float* wb      = (const float*)d_in[3];
    const float* ab      = (const float*)d_in[4];
    const float* ag      = (const float*)d_in[5];
    float* out = (float*)d_out;

    hipMemsetAsync(out, 0, (size_t)out_size * sizeof(float), stream);  // d_out is poisoned before every launch
    loss_kernel<<<dim3(GRID), dim3(256), 0, stream>>>(outputs, oc, labels, wb, ab, ag, out);
}